// Round 10
// baseline (380.600 us; speedup 1.0000x reference)
//
#include <hip/hip_runtime.h>

// ---------------------------------------------------------------------------
// Problem constants (B=2, S=2048, D=1024, H=16, DK=64, DFF=4096)
// External I/O FP32; internal GEMM operands bf16 (MFMA), fp32 accumulate.
// ---------------------------------------------------------------------------
#define BATCH 2
#define SEQ   2048
#define DMODEL 1024
#define NHEAD 16
#define DHEAD 64
#define DFF_  4096
#define MROWS (BATCH*SEQ)   // 4096
#define EPS 1e-6f

typedef unsigned short u16;
typedef unsigned int u32;
typedef __bf16 bf16x8 __attribute__((ext_vector_type(8)));
typedef float  f32x4  __attribute__((ext_vector_type(4)));
typedef u32    u32x2  __attribute__((ext_vector_type(2)));

__device__ __forceinline__ float bf2f(u16 h) {
    union { u32 u; float f; } v; v.u = ((u32)h) << 16; return v.f;
}
__device__ __forceinline__ u16 f2bf(float f) {
    union { float f; u32 u; } v; v.f = f;
    u32 u = v.u;
    u32 r = (u + 0x7fffu + ((u >> 16) & 1u)) >> 16;
    return (u16)r;
}

// async global->LDS DMA, 16 B per lane; LDS dest is wave-uniform base + lane*16
__device__ __forceinline__ void async16(const u16* g, u16* l) {
    __builtin_amdgcn_global_load_lds((const __attribute__((address_space(1))) void*)g,
                                     (__attribute__((address_space(3))) void*)l,
                                     16, 0, 0);
}

// ---------------------------------------------------------------------------
// Merged weight transpose+convert: ALL six weight matrices in ONE launch.
// 1-D grid of 12288 tiles of 32x32, block (32,8).
// ---------------------------------------------------------------------------
__global__ __launch_bounds__(256) void transpose_all(
        const float* __restrict__ wq, const float* __restrict__ wk,
        const float* __restrict__ wv, const float* __restrict__ wo,
        const float* __restrict__ w1, const float* __restrict__ w2,
        u16* __restrict__ wqkvT, u16* __restrict__ woT,
        u16* __restrict__ w1T, u16* __restrict__ w2T) {
    __shared__ float tile[32][33];
    int id = blockIdx.x;
    const float* in; u16* out; int R, C, tx, ty;
    if (id < 4096) {
        int m = id >> 10, t2 = id & 1023;   // four 1024^2: 32x32 tile grid
        tx = t2 & 31; ty = t2 >> 5;
        R = DMODEL; C = DMODEL;
        switch (m) {
            case 0: in = wq; out = wqkvT;                 break;
            case 1: in = wk; out = wqkvT + 1024 * 1024;   break;
            case 2: in = wv; out = wqkvT + 2 * 1024 * 1024; break;
            default: in = wo; out = woT;                  break;
        }
    } else if (id < 8192) {
        int t2 = id - 4096;                 // w1: 128 c-tiles x 32 r-tiles
        tx = t2 & 127; ty = t2 >> 7;
        R = DMODEL; C = DFF_;
        in = w1; out = w1T;
    } else {
        int t2 = id - 8192;                 // w2: 32 c-tiles x 128 r-tiles
        tx = t2 & 31; ty = t2 >> 5;
        R = DFF_; C = DMODEL;
        in = w2; out = w2T;
    }
    int c0 = tx * 32, r0 = ty * 32;
    int x = threadIdx.x, y = threadIdx.y;
    #pragma unroll
    for (int i = 0; i < 32; i += 8)
        tile[y + i][x] = in[(size_t)(r0 + y + i) * C + c0 + x];
    __syncthreads();
    #pragma unroll
    for (int i = 0; i < 32; i += 8)
        out[(size_t)(c0 + y + i) * R + r0 + x] = f2bf(tile[x][y + i]);
}

// ---------------------------------------------------------------------------
// Per-head V transpose WITH per-64-tile key permutation pi(c)=(c&3)*16+(c>>2):
//   vtp[b][h][d][kt + c] = V[b][kt + pi(c)][h*64 + d]
// ---------------------------------------------------------------------------
__global__ __launch_bounds__(256) void transpose_v_perm(const u16* __restrict__ qkv,
                                                        u16* __restrict__ vtp) {
    __shared__ u16 tile[64][72];   // [key_local][d]
    int kt = blockIdx.x * 64;
    int bh = blockIdx.y; int b = bh >> 4, h = bh & 15;
    const u16* in = qkv + ((size_t)(b * SEQ + kt)) * 3072 + 2 * DMODEL + h * DHEAD;
    u16* out = vtp + ((size_t)bh * DHEAD) * SEQ;
    int t = threadIdx.x;
    int r = t >> 3, c8 = (t & 7) * 8;
    #pragma unroll
    for (int pass = 0; pass < 2; pass++) {
        int row = r + pass * 32;
        uint4 v = *(const uint4*)(in + (size_t)row * 3072 + c8);
        *(uint4*)&tile[row][c8] = v;
    }
    __syncthreads();
    #pragma unroll
    for (int pass = 0; pass < 2; pass++) {
        int d = r + pass * 32;
        u16 o8[8];
        #pragma unroll
        for (int e = 0; e < 8; e++) {
            int c = c8 + e;
            o8[e] = tile[(c & 3) * 16 + (c >> 2)][d];
        }
        *(uint4*)(out + (size_t)d * SEQ + kt + c8) = *(const uint4*)o8;
    }
}

// ---------------------------------------------------------------------------
// LayerNorm (TF-style: biased std, eps added to std), row length 1024.
// ---------------------------------------------------------------------------
__global__ __launch_bounds__(256) void ln_kernel(const float* __restrict__ x,
                                                 const float* __restrict__ alpha,
                                                 const float* __restrict__ beta,
                                                 u16* __restrict__ out) {
    int row = blockIdx.x;
    int t = threadIdx.x;
    const float* xr = x + (size_t)row * DMODEL;
    float4 xv = ((const float4*)xr)[t];
    float f0 = xv.x, f1 = xv.y, f2 = xv.z, f3 = xv.w;
    float s1 = f0 + f1 + f2 + f3;
    float s2 = f0*f0 + f1*f1 + f2*f2 + f3*f3;
    #pragma unroll
    for (int off = 32; off >= 1; off >>= 1) {
        s1 += __shfl_xor(s1, off);
        s2 += __shfl_xor(s2, off);
    }
    __shared__ float r1[4], r2[4];
    int w = t >> 6, lane = t & 63;
    if (lane == 0) { r1[w] = s1; r2[w] = s2; }
    __syncthreads();
    s1 = r1[0] + r1[1] + r1[2] + r1[3];
    s2 = r2[0] + r2[1] + r2[2] + r2[3];
    float mean = s1 * (1.0f / DMODEL);
    float var  = s2 * (1.0f / DMODEL) - mean * mean;
    var = fmaxf(var, 0.0f);
    float inv = 1.0f / (sqrtf(var) + EPS);
    float4 av = ((const float4*)alpha)[t];
    float4 bv = ((const float4*)beta)[t];
    ushort4 ov;
    ov.x = f2bf(av.x * (f0 - mean) * inv + bv.x);
    ov.y = f2bf(av.y * (f1 - mean) * inv + bv.y);
    ov.z = f2bf(av.z * (f2 - mean) * inv + bv.z);
    ov.w = f2bf(av.w * (f3 - mean) * inv + bv.w);
    ((ushort4*)(out + (size_t)row * DMODEL))[t] = ov;
}

// ---------------------------------------------------------------------------
// MFMA GEMM (m97 structure, tile-templated). SWAP=false: column banding per
// XCD (QKV/FFN1). SWAP=true: row banding (o-proj/FFN2) — round-9 validated
// (FFN2 left the top-5; flash FETCH model confirmed flat%8 XCD mapping).
// ---------------------------------------------------------------------------
#define BK 64

template <int AI, int AJ, bool OUT_F32, bool SWAP = false>
__global__ __launch_bounds__(256) void gemm_bt(const u16* __restrict__ A,
                                               const u16* __restrict__ BT,
                                               void* __restrict__ Cp,
                                               const float* __restrict__ bias,
                                               const float* __restrict__ residual,
                                               int M, int N, int K, int do_relu) {
    constexpr int BMt = AI * 32, BNt = AJ * 32;
    __shared__ u16 As[BMt * BK];   // row-major stride 64, swizzled k-slots
    __shared__ u16 Bs[BNt * BK];
    int t = threadIdx.x;
    int bx = blockIdx.x;
    if ((gridDim.x & 7) == 0) {            // XCD banding remap (bijective)
        int cpx = gridDim.x >> 3;
        bx = (bx & 7) * cpx + (bx >> 3);
    }
    int mt = SWAP ? bx : (int)blockIdx.y;  // row-tile index
    int nt = SWAP ? (int)blockIdx.y : bx;  // col-tile index
    int m0 = mt * BMt, n0 = nt * BNt;
    int lane = t & 63, w = t >> 6;
    int wr = w >> 1, wc = w & 1;
    int lhi = lane >> 4, llo = lane & 15;
    int sr = lane >> 3, sk = lane & 7;     // staging: 8 lanes per row
    int skx = (sk ^ sr) * 8;               // swizzled k-block (row&7 == sr)

    f32x4 acc[AI][AJ] = {};

    const u16* Ab = A  + (size_t)m0 * K + skx;
    const u16* Bb = BT + (size_t)n0 * K + skx;

    for (int k0 = 0; k0 < K; k0 += BK) {
        __syncthreads();
        #pragma unroll
        for (int j = 0; j < AI; j++) {
            int blk = w * AI + j;          // stages rows blk*8 .. blk*8+7
            async16(Ab + (size_t)(blk * 8 + sr) * K + k0, &As[blk * 512]);
        }
        #pragma unroll
        for (int j = 0; j < AJ; j++) {
            int blk = w * AJ + j;
            async16(Bb + (size_t)(blk * 8 + sr) * K + k0, &Bs[blk * 512]);
        }
        __syncthreads();   // drains vmcnt (global_load_lds) before frag reads
        #pragma unroll
        for (int kk = 0; kk < 2; kk++) {
            int slot = ((kk * 4 + lhi) ^ (llo & 7)) * 8;
            bf16x8 af[AI], bfr[AJ];
            #pragma unroll
            for (int i = 0; i < AI; i++)
                af[i]  = *(const bf16x8*)(&As[(wr * 16 * AI + i * 16 + llo) * 64 + slot]);
            #pragma unroll
            for (int j = 0; j < AJ; j++)
                bfr[j] = *(const bf16x8*)(&Bs[(wc * 16 * AJ + j * 16 + llo) * 64 + slot]);
            #pragma unroll
            for (int i = 0; i < AI; i++)
                #pragma unroll
                for (int j = 0; j < AJ; j++)
                    acc[i][j] = __builtin_amdgcn_mfma_f32_16x16x32_bf16(af[i], bfr[j], acc[i][j], 0, 0, 0);
        }
    }

    #pragma unroll
    for (int i = 0; i < AI; i++) {
        #pragma unroll
        for (int rr = 0; rr < 4; rr++) {
            int row = m0 + wr * 16 * AI + i * 16 + lhi * 4 + rr;
            #pragma unroll
            for (int j = 0; j < AJ; j++) {
                int col = n0 + wc * 16 * AJ + j * 16 + llo;
                float v = acc[i][j][rr];
                if (bias)      v += bias[col];
                if (residual)  v += residual[(size_t)row * N + col];
                if (do_relu)   v = fmaxf(v, 0.0f);
                size_t idx = (size_t)row * N + col;
                if (OUT_F32) ((float*)Cp)[idx] = v;
                else         ((u16*)Cp)[idx]   = f2bf(v);
            }
        }
    }
}

// ---------------------------------------------------------------------------
// Flash attention v5 body, round-10 KEY-SPLIT (flash-decoding, KSPLIT=2):
// grid (32,16,4) = 2048 blocks; each block handles HALF the keys (16 tiles
// of 64) for one (q-tile, head, batch). Rationale: round-9 showed K/V fully
// L2-resident (FETCH 69.7->12.3MB) yet dur ~unchanged -> stall-bound, not
// feed-bound; LDS pipe ~55%, duration tracked resident parallelism all
// session. Split keeps per-CU staging/LDS traffic IDENTICAL (v9's killer:
// it doubled traffic), raises residency 4->6 blocks/CU (LDS 25KB, 160/25=6)
// and halves each block's serial barrier chain (32->16 iters).
// Partial outputs: NORMALIZED O (bf16, same rounding as before) to po0/po1,
// partial l (fp32) to pl; tiny combine kernel merges.
// XCD clustering: flat f -> q=f>>6, r=f&63, unit u=(r&7)*8+(r>>3);
// XCD k owns units [8k,8k+8) = 4 (b,h) x 2 halves = 2MB K/V. Bijective.
// ---------------------------------------------------------------------------
#define SCL 0.18033688f   // log2(e)/8

__global__ __launch_bounds__(256) void flash_attn(const u16* __restrict__ qkv,
                                                  const u16* __restrict__ vtp,
                                                  const int* __restrict__ mask,
                                                  u16* __restrict__ po0,
                                                  u16* __restrict__ po1,
                                                  float* __restrict__ pl) {
    __shared__ u16 QPs[64 * 64];   // 8KB: Q staging, then per-wave P (w*1024)
    __shared__ u16 Ks[64 * 64];
    __shared__ u16 VTs[64 * 64];
    __shared__ float mbias[64];

    int t = threadIdx.x;
    int w = t >> 6, lane = t & 63, lhi = lane >> 4, llo = lane & 15;
    int sr = lane >> 3, sk = lane & 7;
    int skx = (sk ^ sr) * 8;

    // XCD-aware (q-tile, unit) assignment — bijective remap
    int f  = (blockIdx.z * NHEAD + blockIdx.y) * (SEQ / 64) + blockIdx.x;
    int q0 = (f >> 6) * 64;
    int r  = f & 63;
    int u  = (r & 7) * 8 + (r >> 3);       // XCD = r&7 owns units [8k,8k+8)
    int b = u >> 5, h = (u >> 1) & 15, half = u & 1;
    int kbase = half * (SEQ / 2);

    const u16* Qg  = qkv + ((size_t)(b * SEQ + q0)) * 3072 + h * DHEAD;
    const u16* Kg  = qkv + ((size_t)(b * SEQ)) * 3072 + DMODEL + h * DHEAD;
    const u16* VTg = vtp + ((size_t)((b * NHEAD + h) * DHEAD)) * SEQ;  // [d][key']

    // ---- stage Q via DMA: 64 rows x 64 d (2 rounds), swizzled d-blocks ----
    #pragma unroll
    for (int j = 0; j < 2; j++) {
        int blk = w * 2 + j;
        async16(Qg + (size_t)(blk * 8 + sr) * 3072 + skx, &QPs[blk * 512]);
    }
    __syncthreads();
    bf16x8 qf[2];
    #pragma unroll
    for (int kk = 0; kk < 2; kk++)
        qf[kk] = *(const bf16x8*)&QPs[(w * 16 + llo) * 64 + ((kk * 4 + lhi) ^ (llo & 7)) * 8];

    u16* Ps = QPs + w * 1024;   // per-wave 16 x 64 P tile, stride 64, swizzled

    float l_part[4] = {};
    f32x4 o_acc[4] = {};

    for (int kt = kbase; kt < kbase + SEQ / 2; kt += 64) {
        __syncthreads();   // prev-iter Ks/VTs reads done; guards Q->Ps alias
        #pragma unroll
        for (int j = 0; j < 2; j++) {
            int blk = w * 2 + j;
            async16(Kg  + (size_t)(kt + blk * 8 + sr) * 3072 + skx, &Ks[blk * 512]);
            async16(VTg + (size_t)(blk * 8 + sr) * SEQ + kt + skx,  &VTs[blk * 512]);
        }
        if (t < 64) mbias[t] = (mask[b * SEQ + kt + t] == 0) ? -1.0e12f : 0.0f;
        __syncthreads();

        // ---- S = Q K^T: 16 q x 64 keys per wave ----
        f32x4 s4[4] = {};
        __builtin_amdgcn_s_setprio(1);
        #pragma unroll
        for (int kk = 0; kk < 2; kk++) {
            #pragma unroll
            for (int j = 0; j < 4; j++) {
                bf16x8 kf = *(const bf16x8*)&Ks[(j * 16 + llo) * 64 +
                                                ((kk * 4 + lhi) ^ (llo & 7)) * 8];
                s4[j] = __builtin_amdgcn_mfma_f32_16x16x32_bf16(qf[kk], kf, s4[j], 0, 0, 0);
            }
        }
        __builtin_amdgcn_s_setprio(0);
        // ---- mask bias (orig key order: col j*16+llo) ----
        float mb[4];
        #pragma unroll
        for (int j = 0; j < 4; j++) mb[j] = mbias[j * 16 + llo];

        // ---- p = 2^(s*SCL + mb); permuted+swizzled b64 store; l sum ----
        #pragma unroll
        for (int rr = 0; rr < 4; rr++) {
            u32 pu[4];
            #pragma unroll
            for (int j = 0; j < 4; j++) {
                float p = __builtin_amdgcn_exp2f(__builtin_fmaf(s4[j][rr], SCL, mb[j]));
                l_part[rr] += p;
                union { float f; u32 u; } c; c.f = p;
                pu[j] = c.u;
            }
            u32x2 pw;
            pw[0] = (pu[0] >> 16) | (pu[1] & 0xffff0000u);
            pw[1] = (pu[2] >> 16) | (pu[3] & 0xffff0000u);
            int prow = lhi * 4 + rr;
            *(u32x2*)&Ps[prow * 64 + ((llo >> 1) ^ (prow & 7)) * 8 + (llo & 1) * 4] = pw;
        }
        // ---- O += P V (pf single b128; same swizzle family as kf/vf) ----
        __builtin_amdgcn_s_setprio(1);
        #pragma unroll
        for (int kk = 0; kk < 2; kk++) {
            bf16x8 pf = *(const bf16x8*)&Ps[llo * 64 + ((kk * 4 + lhi) ^ (llo & 7)) * 8];
            #pragma unroll
            for (int nb = 0; nb < 4; nb++) {
                bf16x8 vf = *(const bf16x8*)&VTs[(nb * 16 + llo) * 64 +
                                                 ((kk * 4 + lhi) ^ (llo & 7)) * 8];
                o_acc[nb] = __builtin_amdgcn_mfma_f32_16x16x32_bf16(pf, vf, o_acc[nb], 0, 0, 0);
            }
        }
        __builtin_amdgcn_s_setprio(0);
    }

    // ---- epilogue: reduce l, write NORMALIZED partial O + partial l ----
    u16* po = half ? po1 : po0;
    #pragma unroll
    for (int rr = 0; rr < 4; rr++) {
        float l = l_part[rr];
        #pragma unroll
        for (int off = 1; off <= 8; off <<= 1) l += __shfl_xor(l, off);
        float inv = __builtin_amdgcn_rcpf(l);
        int row = q0 + w * 16 + lhi * 4 + rr;
        #pragma unroll
        for (int nb = 0; nb < 4; nb++) {
            int col = h * DHEAD + nb * 16 + llo;
            po[((size_t)(b * SEQ) + row) * DMODEL + col] = f2bf(o_acc[nb][rr] * inv);
        }
        if (llo == 0)
            pl[(((size_t)half * BATCH + b) * NHEAD + h) * SEQ + row] = l;
    }
}

// ---------------------------------------------------------------------------
// Combine the two key-half partials: ctx = (l0*n0 + l1*n1) / (l0+l1).
// In place over po0 (each element read then written by the same thread).
// grid MROWS, block 256, 4 cols/thread.
// ---------------------------------------------------------------------------
__global__ __launch_bounds__(256) void attn_combine(u16* po0,
                                                    const u16* __restrict__ po1,
                                                    const float* __restrict__ pl) {
    int row = blockIdx.x;             // b*SEQ + seq
    int b = row >> 11, seq = row & (SEQ - 1);
    int t = threadIdx.x;
    int h = t >> 4;                   // (t*4)>>6
    float l0 = pl[(((size_t)0 * BATCH + b) * NHEAD + h) * SEQ + seq];
    float l1 = pl[(((size_t)1 * BATCH + b) * NHEAD + h) * SEQ + seq];
    float inv = __builtin_amdgcn_rcpf(l0 + l1);
    float w0 = l0 * inv, w1 = l1 * inv;
    ushort4 a = ((const ushort4*)(po0 + (size_t)row * DMODEL))[t];
    ushort4 c = ((const ushort4*)(po1 + (size_t)row * DMODEL))[t];
    ushort4 o;
    o.x = f2bf(bf2f(a.x) * w0 + bf2f(c.x) * w1);
    o.y = f2bf(bf2f(a.y) * w0 + bf2f(c.y) * w1);
    o.z = f2bf(bf2f(a.z) * w0 + bf2f(c.z) * w1);
    o.w = f2bf(bf2f(a.w) * w0 + bf2f(c.w) * w1);
    ((ushort4*)(po0 + (size_t)row * DMODEL))[t] = o;
}

// ---------------------------------------------------------------------------
// Host launcher
// ---------------------------------------------------------------------------
extern "C" void kernel_launch(void* const* d_in, const int* in_sizes, int n_in,
                              void* d_out, int out_size, void* d_ws, size_t ws_size,
                              hipStream_t stream) {
    (void)in_sizes; (void)n_in; (void)out_size; (void)ws_size;
    const float* x    = (const float*)d_in[0];
    const int* mask   = (const int*)d_in[1];
    const float* wq   = (const float*)d_in[2];
    const float* wk   = (const float*)d_in[3];
    const float* wv   = (const float*)d_in[4];
    const float* wo   = (const float*)d_in[5];
    const float* w1   = (const float*)d_in[6];
    const float* b1   = (const float*)d_in[7];
    const float* w2   = (const float*)d_in[8];
    const float* b2   = (const float*)d_in[9];
    const float* ln1a = (const float*)d_in[10];
    const float* ln1b = (const float*)d_in[11];
    const float* ln2a = (const float*)d_in[12];
    const float* ln2b = (const float*)d_in[13];
    float* out = (float*)d_out;

    // Workspace layout (byte offsets, MB):
    // [0,6) wqkvT | [6,8) woT | [8,16) w1T | [16,24) w2T | [24,32) xn
    //   (pl aliases [24,24.5) during attention+combine; xn dead there)
    // [32,48) x2 fp32; during attention phase: vtp [32,40), po1 [40,48)
    // [48,56) ctx (= po0: combine merges in place) | [56,88) qkv / ff1
    char* wsb = (char*)d_ws;
    const size_t MB = 1024 * 1024;
    u16*   wqkvT = (u16*)(wsb + 0);
    u16*   woT   = (u16*)(wsb + 6 * MB);
    u16*   w1T   = (u16*)(wsb + 8 * MB);
    u16*   w2T   = (u16*)(wsb + 16 * MB);
    u16*   xn    = (u16*)(wsb + 24 * MB);
    float* pl    = (float*)(wsb + 24 * MB);   // 512KB, xn dead during attn
    float* x2    = (float*)(wsb + 32 * MB);
    u16*   vtp   = (u16*)(wsb + 32 * MB);   // bf16 [2][16][64][2048] perm, 8 MB
    u16*   po1   = (u16*)(wsb + 40 * MB);   // key-half-1 partial O, 8 MB
    u16*   ctx   = (u16*)(wsb + 48 * MB);   // = po0
    u16*   qkv   = (u16*)(wsb + 56 * MB);
    u16*   ff1   = (u16*)(wsb + 56 * MB);

    // merged weight transposes: one launch for wq/wk/wv/wo/w1/w2
    transpose_all<<<12288, dim3(32, 8), 0, stream>>>(
        wq, wk, wv, wo, w1, w2,
        wqkvT, woT, w1T, w2T);

    // LN1: xn = LN(x)
    ln_kernel<<<MROWS, 256, 0, stream>>>(x, ln1a, ln1b, xn);
    // QKV GEMM: [4096,1024]@[1024,3072], 128x64 tiles (1536 blocks, 6/CU)
    gemm_bt<4,2,false><<<dim3(3072/64, MROWS/128), 256, 0, stream>>>(xn, wqkvT, qkv,
                                                                     nullptr, nullptr,
                                                                     MROWS, 3072, DMODEL, 0);
    // V transpose (key-permuted) for DMA + b64-P staging
    transpose_v_perm<<<dim3(SEQ/64, BATCH*NHEAD), 256, 0, stream>>>(qkv, vtp);
    // flash attention, key-split x2 -> normalized partials + l
    flash_attn<<<dim3(SEQ/64, NHEAD, BATCH*2), 256, 0, stream>>>(qkv, vtp, mask,
                                                                 ctx, po1, pl);
    // merge key-halves in place into ctx
    attn_combine<<<MROWS, 256, 0, stream>>>(ctx, po1, pl);
    // O-projection + residual: x2 = x + ctx @ wo, 64x64 tiles, ROW-banded
    gemm_bt<2,2,true,true><<<dim3(MROWS/64, DMODEL/64), 256, 0, stream>>>(
        ctx, woT, x2, nullptr, x, MROWS, DMODEL, DMODEL, 0);
    // LN2
    ln_kernel<<<MROWS, 256, 0, stream>>>(x2, ln2a, ln2b, xn);
    // FFN1: ff1 = relu(xn @ w1 + b1), 128x64 tiles (2048 blocks, 6/CU by LDS)
    gemm_bt<4,2,false><<<dim3(DFF_/64, MROWS/128), 256, 0, stream>>>(xn, w1T, ff1,
                                                                    b1, nullptr,
                                                                    MROWS, DFF_, DMODEL, 1);
    // FFN2: out = x2 + ff1 @ w2 + b2, 64x64 tiles, ROW-banded grid (64,16)
    gemm_bt<2,2,true,true><<<dim3(MROWS/64, DMODEL/64), 256, 0, stream>>>(
        ff1, w2T, out, b2, x2, MROWS, DMODEL, DFF_, 0);
}

// Round 11
// 352.917 us; speedup vs baseline: 1.0784x; 1.0784x over previous
//
#include <hip/hip_runtime.h>

// ---------------------------------------------------------------------------
// Problem constants (B=2, S=2048, D=1024, H=16, DK=64, DFF=4096)
// External I/O FP32; internal GEMM operands bf16 (MFMA), fp32 accumulate.
// ---------------------------------------------------------------------------
#define BATCH 2
#define SEQ   2048
#define DMODEL 1024
#define NHEAD 16
#define DHEAD 64
#define DFF_  4096
#define MROWS (BATCH*SEQ)   // 4096
#define EPS 1e-6f

typedef unsigned short u16;
typedef unsigned int u32;
typedef __bf16 bf16x8 __attribute__((ext_vector_type(8)));
typedef float  f32x4  __attribute__((ext_vector_type(4)));
typedef u32    u32x2  __attribute__((ext_vector_type(2)));

__device__ __forceinline__ float bf2f(u16 h) {
    union { u32 u; float f; } v; v.u = ((u32)h) << 16; return v.f;
}
__device__ __forceinline__ u16 f2bf(float f) {
    union { float f; u32 u; } v; v.f = f;
    u32 u = v.u;
    u32 r = (u + 0x7fffu + ((u >> 16) & 1u)) >> 16;
    return (u16)r;
}

// async global->LDS DMA, 16 B per lane; LDS dest is wave-uniform base + lane*16
__device__ __forceinline__ void async16(const u16* g, u16* l) {
    __builtin_amdgcn_global_load_lds((const __attribute__((address_space(1))) void*)g,
                                     (__attribute__((address_space(3))) void*)l,
                                     16, 0, 0);
}

// ---------------------------------------------------------------------------
// Merged weight transpose+convert: ALL six weight matrices in ONE launch.
// 1-D grid of 12288 tiles of 32x32, block (32,8).
// ---------------------------------------------------------------------------
__global__ __launch_bounds__(256) void transpose_all(
        const float* __restrict__ wq, const float* __restrict__ wk,
        const float* __restrict__ wv, const float* __restrict__ wo,
        const float* __restrict__ w1, const float* __restrict__ w2,
        u16* __restrict__ wqkvT, u16* __restrict__ woT,
        u16* __restrict__ w1T, u16* __restrict__ w2T) {
    __shared__ float tile[32][33];
    int id = blockIdx.x;
    const float* in; u16* out; int R, C, tx, ty;
    if (id < 4096) {
        int m = id >> 10, t2 = id & 1023;   // four 1024^2: 32x32 tile grid
        tx = t2 & 31; ty = t2 >> 5;
        R = DMODEL; C = DMODEL;
        switch (m) {
            case 0: in = wq; out = wqkvT;                 break;
            case 1: in = wk; out = wqkvT + 1024 * 1024;   break;
            case 2: in = wv; out = wqkvT + 2 * 1024 * 1024; break;
            default: in = wo; out = woT;                  break;
        }
    } else if (id < 8192) {
        int t2 = id - 4096;                 // w1: 128 c-tiles x 32 r-tiles
        tx = t2 & 127; ty = t2 >> 7;
        R = DMODEL; C = DFF_;
        in = w1; out = w1T;
    } else {
        int t2 = id - 8192;                 // w2: 32 c-tiles x 128 r-tiles
        tx = t2 & 31; ty = t2 >> 5;
        R = DFF_; C = DMODEL;
        in = w2; out = w2T;
    }
    int c0 = tx * 32, r0 = ty * 32;
    int x = threadIdx.x, y = threadIdx.y;
    #pragma unroll
    for (int i = 0; i < 32; i += 8)
        tile[y + i][x] = in[(size_t)(r0 + y + i) * C + c0 + x];
    __syncthreads();
    #pragma unroll
    for (int i = 0; i < 32; i += 8)
        out[(size_t)(c0 + y + i) * R + r0 + x] = f2bf(tile[x][y + i]);
}

// ---------------------------------------------------------------------------
// Per-head V transpose WITH per-64-tile key permutation pi(c)=(c&3)*16+(c>>2):
//   vtp[b][h][d][kt + c] = V[b][kt + pi(c)][h*64 + d]
// ---------------------------------------------------------------------------
__global__ __launch_bounds__(256) void transpose_v_perm(const u16* __restrict__ qkv,
                                                        u16* __restrict__ vtp) {
    __shared__ u16 tile[64][72];   // [key_local][d]
    int kt = blockIdx.x * 64;
    int bh = blockIdx.y; int b = bh >> 4, h = bh & 15;
    const u16* in = qkv + ((size_t)(b * SEQ + kt)) * 3072 + 2 * DMODEL + h * DHEAD;
    u16* out = vtp + ((size_t)bh * DHEAD) * SEQ;
    int t = threadIdx.x;
    int r = t >> 3, c8 = (t & 7) * 8;
    #pragma unroll
    for (int pass = 0; pass < 2; pass++) {
        int row = r + pass * 32;
        uint4 v = *(const uint4*)(in + (size_t)row * 3072 + c8);
        *(uint4*)&tile[row][c8] = v;
    }
    __syncthreads();
    #pragma unroll
    for (int pass = 0; pass < 2; pass++) {
        int d = r + pass * 32;
        u16 o8[8];
        #pragma unroll
        for (int e = 0; e < 8; e++) {
            int c = c8 + e;
            o8[e] = tile[(c & 3) * 16 + (c >> 2)][d];
        }
        *(uint4*)(out + (size_t)d * SEQ + kt + c8) = *(const uint4*)o8;
    }
}

// ---------------------------------------------------------------------------
// LayerNorm (TF-style: biased std, eps added to std), row length 1024.
// ---------------------------------------------------------------------------
__global__ __launch_bounds__(256) void ln_kernel(const float* __restrict__ x,
                                                 const float* __restrict__ alpha,
                                                 const float* __restrict__ beta,
                                                 u16* __restrict__ out) {
    int row = blockIdx.x;
    int t = threadIdx.x;
    const float* xr = x + (size_t)row * DMODEL;
    float4 xv = ((const float4*)xr)[t];
    float f0 = xv.x, f1 = xv.y, f2 = xv.z, f3 = xv.w;
    float s1 = f0 + f1 + f2 + f3;
    float s2 = f0*f0 + f1*f1 + f2*f2 + f3*f3;
    #pragma unroll
    for (int off = 32; off >= 1; off >>= 1) {
        s1 += __shfl_xor(s1, off);
        s2 += __shfl_xor(s2, off);
    }
    __shared__ float r1[4], r2[4];
    int w = t >> 6, lane = t & 63;
    if (lane == 0) { r1[w] = s1; r2[w] = s2; }
    __syncthreads();
    s1 = r1[0] + r1[1] + r1[2] + r1[3];
    s2 = r2[0] + r2[1] + r2[2] + r2[3];
    float mean = s1 * (1.0f / DMODEL);
    float var  = s2 * (1.0f / DMODEL) - mean * mean;
    var = fmaxf(var, 0.0f);
    float inv = 1.0f / (sqrtf(var) + EPS);
    float4 av = ((const float4*)alpha)[t];
    float4 bv = ((const float4*)beta)[t];
    ushort4 ov;
    ov.x = f2bf(av.x * (f0 - mean) * inv + bv.x);
    ov.y = f2bf(av.y * (f1 - mean) * inv + bv.y);
    ov.z = f2bf(av.z * (f2 - mean) * inv + bv.z);
    ov.w = f2bf(av.w * (f3 - mean) * inv + bv.w);
    ((ushort4*)(out + (size_t)row * DMODEL))[t] = ov;
}

// ---------------------------------------------------------------------------
// MFMA GEMM (m97 structure, tile-templated). SWAP=false: column banding per
// XCD (QKV/FFN1). SWAP=true: row banding (o-proj/FFN2) — round-9 validated
// (FFN2 left the top-5; flash FETCH model confirmed flat%8 XCD mapping).
// ---------------------------------------------------------------------------
#define BK 64

template <int AI, int AJ, bool OUT_F32, bool SWAP = false>
__global__ __launch_bounds__(256) void gemm_bt(const u16* __restrict__ A,
                                               const u16* __restrict__ BT,
                                               void* __restrict__ Cp,
                                               const float* __restrict__ bias,
                                               const float* __restrict__ residual,
                                               int M, int N, int K, int do_relu) {
    constexpr int BMt = AI * 32, BNt = AJ * 32;
    __shared__ u16 As[BMt * BK];   // row-major stride 64, swizzled k-slots
    __shared__ u16 Bs[BNt * BK];
    int t = threadIdx.x;
    int bx = blockIdx.x;
    if ((gridDim.x & 7) == 0) {            // XCD banding remap (bijective)
        int cpx = gridDim.x >> 3;
        bx = (bx & 7) * cpx + (bx >> 3);
    }
    int mt = SWAP ? bx : (int)blockIdx.y;  // row-tile index
    int nt = SWAP ? (int)blockIdx.y : bx;  // col-tile index
    int m0 = mt * BMt, n0 = nt * BNt;
    int lane = t & 63, w = t >> 6;
    int wr = w >> 1, wc = w & 1;
    int lhi = lane >> 4, llo = lane & 15;
    int sr = lane >> 3, sk = lane & 7;     // staging: 8 lanes per row
    int skx = (sk ^ sr) * 8;               // swizzled k-block (row&7 == sr)

    f32x4 acc[AI][AJ] = {};

    const u16* Ab = A  + (size_t)m0 * K + skx;
    const u16* Bb = BT + (size_t)n0 * K + skx;

    for (int k0 = 0; k0 < K; k0 += BK) {
        __syncthreads();
        #pragma unroll
        for (int j = 0; j < AI; j++) {
            int blk = w * AI + j;          // stages rows blk*8 .. blk*8+7
            async16(Ab + (size_t)(blk * 8 + sr) * K + k0, &As[blk * 512]);
        }
        #pragma unroll
        for (int j = 0; j < AJ; j++) {
            int blk = w * AJ + j;
            async16(Bb + (size_t)(blk * 8 + sr) * K + k0, &Bs[blk * 512]);
        }
        __syncthreads();   // drains vmcnt (global_load_lds) before frag reads
        #pragma unroll
        for (int kk = 0; kk < 2; kk++) {
            int slot = ((kk * 4 + lhi) ^ (llo & 7)) * 8;
            bf16x8 af[AI], bfr[AJ];
            #pragma unroll
            for (int i = 0; i < AI; i++)
                af[i]  = *(const bf16x8*)(&As[(wr * 16 * AI + i * 16 + llo) * 64 + slot]);
            #pragma unroll
            for (int j = 0; j < AJ; j++)
                bfr[j] = *(const bf16x8*)(&Bs[(wc * 16 * AJ + j * 16 + llo) * 64 + slot]);
            #pragma unroll
            for (int i = 0; i < AI; i++)
                #pragma unroll
                for (int j = 0; j < AJ; j++)
                    acc[i][j] = __builtin_amdgcn_mfma_f32_16x16x32_bf16(af[i], bfr[j], acc[i][j], 0, 0, 0);
        }
    }

    #pragma unroll
    for (int i = 0; i < AI; i++) {
        #pragma unroll
        for (int rr = 0; rr < 4; rr++) {
            int row = m0 + wr * 16 * AI + i * 16 + lhi * 4 + rr;
            #pragma unroll
            for (int j = 0; j < AJ; j++) {
                int col = n0 + wc * 16 * AJ + j * 16 + llo;
                float v = acc[i][j][rr];
                if (bias)      v += bias[col];
                if (residual)  v += residual[(size_t)row * N + col];
                if (do_relu)   v = fmaxf(v, 0.0f);
                size_t idx = (size_t)row * N + col;
                if (OUT_F32) ((float*)Cp)[idx] = v;
                else         ((u16*)Cp)[idx]   = f2bf(v);
            }
        }
    }
}

// ---------------------------------------------------------------------------
// Flash attention v5 body + XCD head clustering + s_setprio (round-9 best:
// 64.2us, FETCH 12.35MB = near-ideal). Block 256 thr (4 waves), Q-tile 64
// (wave owns 16 q), 32 K/V tiles of 64 keys. grid (32,16,2)=1024 -> 4/CU.
// XCD remap: flat dispatch f -> s=f&31, q-tile=f>>5; hb=(s&7)*4+(s>>3).
// XCD k hosts (h,b) pairs [4k,4k+4) -> per-XCD K/V working set 2MB,
// L2-resident. Bijective -> correctness-identical.
// Round-10 post-mortem: key-split (2x blocks, half chain) left duration
// unchanged (64.8-65.4) and added combine overhead -> reverted. Duration is
// invariant under parallelism/chain-length/HBM-traffic changes; ~65us is the
// intrinsic cost of this barrier-synced per-iteration structure. Next lever
// would be the full 8-phase counted-vmcnt rewrite (T3+T4), not incremental.
// ---------------------------------------------------------------------------
#define SCL 0.18033688f   // log2(e)/8

__global__ __launch_bounds__(256) void flash_attn(const u16* __restrict__ qkv,
                                                  const u16* __restrict__ vtp,
                                                  const int* __restrict__ mask,
                                                  u16* __restrict__ ctx) {
    __shared__ u16 QPs[64 * 64];   // 8KB: Q staging, then per-wave P (w*1024)
    __shared__ u16 Ks[64 * 64];
    __shared__ u16 VTs[64 * 64];
    __shared__ float mbias[64];

    int t = threadIdx.x;
    int w = t >> 6, lane = t & 63, lhi = lane >> 4, llo = lane & 15;
    int sr = lane >> 3, sk = lane & 7;
    int skx = (sk ^ sr) * 8;

    // XCD-aware (q-tile, head, batch) assignment — bijective remap
    int f  = (blockIdx.z * NHEAD + blockIdx.y) * (SEQ / 64) + blockIdx.x;
    int s  = f & 31;
    int q0 = (f >> 5) * 64;
    int hb = (s & 7) * 4 + (s >> 3);
    int h = hb & 15, b = hb >> 4;

    const u16* Qg  = qkv + ((size_t)(b * SEQ + q0)) * 3072 + h * DHEAD;
    const u16* Kg  = qkv + ((size_t)(b * SEQ)) * 3072 + DMODEL + h * DHEAD;
    const u16* VTg = vtp + ((size_t)((b * NHEAD + h) * DHEAD)) * SEQ;  // [d][key']

    // ---- stage Q via DMA: 64 rows x 64 d (2 rounds), swizzled d-blocks ----
    #pragma unroll
    for (int j = 0; j < 2; j++) {
        int blk = w * 2 + j;
        async16(Qg + (size_t)(blk * 8 + sr) * 3072 + skx, &QPs[blk * 512]);
    }
    __syncthreads();
    bf16x8 qf[2];
    #pragma unroll
    for (int kk = 0; kk < 2; kk++)
        qf[kk] = *(const bf16x8*)&QPs[(w * 16 + llo) * 64 + ((kk * 4 + lhi) ^ (llo & 7)) * 8];

    u16* Ps = QPs + w * 1024;   // per-wave 16 x 64 P tile, stride 64, swizzled

    float l_part[4] = {};
    f32x4 o_acc[4] = {};

    for (int kt = 0; kt < SEQ; kt += 64) {
        __syncthreads();   // prev-iter Ks/VTs reads done; guards Q->Ps alias
        #pragma unroll
        for (int j = 0; j < 2; j++) {
            int blk = w * 2 + j;
            async16(Kg  + (size_t)(kt + blk * 8 + sr) * 3072 + skx, &Ks[blk * 512]);
            async16(VTg + (size_t)(blk * 8 + sr) * SEQ + kt + skx,  &VTs[blk * 512]);
        }
        if (t < 64) mbias[t] = (mask[b * SEQ + kt + t] == 0) ? -1.0e12f : 0.0f;
        __syncthreads();

        // ---- S = Q K^T: 16 q x 64 keys per wave ----
        f32x4 s4[4] = {};
        __builtin_amdgcn_s_setprio(1);
        #pragma unroll
        for (int kk = 0; kk < 2; kk++) {
            #pragma unroll
            for (int j = 0; j < 4; j++) {
                bf16x8 kf = *(const bf16x8*)&Ks[(j * 16 + llo) * 64 +
                                                ((kk * 4 + lhi) ^ (llo & 7)) * 8];
                s4[j] = __builtin_amdgcn_mfma_f32_16x16x32_bf16(qf[kk], kf, s4[j], 0, 0, 0);
            }
        }
        __builtin_amdgcn_s_setprio(0);
        // ---- mask bias (orig key order: col j*16+llo) ----
        float mb[4];
        #pragma unroll
        for (int j = 0; j < 4; j++) mb[j] = mbias[j * 16 + llo];

        // ---- p = 2^(s*SCL + mb); permuted+swizzled b64 store; l sum ----
        #pragma unroll
        for (int rr = 0; rr < 4; rr++) {
            u32 pu[4];
            #pragma unroll
            for (int j = 0; j < 4; j++) {
                float p = __builtin_amdgcn_exp2f(__builtin_fmaf(s4[j][rr], SCL, mb[j]));
                l_part[rr] += p;
                union { float f; u32 u; } c; c.f = p;
                pu[j] = c.u;
            }
            u32x2 pw;
            pw[0] = (pu[0] >> 16) | (pu[1] & 0xffff0000u);
            pw[1] = (pu[2] >> 16) | (pu[3] & 0xffff0000u);
            int prow = lhi * 4 + rr;
            *(u32x2*)&Ps[prow * 64 + ((llo >> 1) ^ (prow & 7)) * 8 + (llo & 1) * 4] = pw;
        }
        // ---- O += P V (pf single b128; same swizzle family as kf/vf) ----
        __builtin_amdgcn_s_setprio(1);
        #pragma unroll
        for (int kk = 0; kk < 2; kk++) {
            bf16x8 pf = *(const bf16x8*)&Ps[llo * 64 + ((kk * 4 + lhi) ^ (llo & 7)) * 8];
            #pragma unroll
            for (int nb = 0; nb < 4; nb++) {
                bf16x8 vf = *(const bf16x8*)&VTs[(nb * 16 + llo) * 64 +
                                                 ((kk * 4 + lhi) ^ (llo & 7)) * 8];
                o_acc[nb] = __builtin_amdgcn_mfma_f32_16x16x32_bf16(pf, vf, o_acc[nb], 0, 0, 0);
            }
        }
        __builtin_amdgcn_s_setprio(0);
    }

    // ---- epilogue: reduce l across the 16 llo lanes, ctx = O / l ----
    #pragma unroll
    for (int rr = 0; rr < 4; rr++) {
        float l = l_part[rr];
        #pragma unroll
        for (int off = 1; off <= 8; off <<= 1) l += __shfl_xor(l, off);
        float inv = __builtin_amdgcn_rcpf(l);
        int row = q0 + w * 16 + lhi * 4 + rr;
        #pragma unroll
        for (int nb = 0; nb < 4; nb++) {
            int col = h * DHEAD + nb * 16 + llo;
            ctx[((size_t)(b * SEQ) + row) * DMODEL + col] = f2bf(o_acc[nb][rr] * inv);
        }
    }
}

// ---------------------------------------------------------------------------
// Host launcher
// ---------------------------------------------------------------------------
extern "C" void kernel_launch(void* const* d_in, const int* in_sizes, int n_in,
                              void* d_out, int out_size, void* d_ws, size_t ws_size,
                              hipStream_t stream) {
    (void)in_sizes; (void)n_in; (void)out_size; (void)ws_size;
    const float* x    = (const float*)d_in[0];
    const int* mask   = (const int*)d_in[1];
    const float* wq   = (const float*)d_in[2];
    const float* wk   = (const float*)d_in[3];
    const float* wv   = (const float*)d_in[4];
    const float* wo   = (const float*)d_in[5];
    const float* w1   = (const float*)d_in[6];
    const float* b1   = (const float*)d_in[7];
    const float* w2   = (const float*)d_in[8];
    const float* b2   = (const float*)d_in[9];
    const float* ln1a = (const float*)d_in[10];
    const float* ln1b = (const float*)d_in[11];
    const float* ln2a = (const float*)d_in[12];
    const float* ln2b = (const float*)d_in[13];
    float* out = (float*)d_out;

    // Workspace layout (byte offsets):
    // [0,6) wqkvT | [6,8) woT | [8,16) w1T | [16,24) w2T | [24,32) xn
    // [32,48) x2 fp32 (vtp aliases [32,40) during attention phase only)
    // [48,56) ctx | [56,80) qkv | [56,88) ff1 (reuse, qkv dead by FFN1)
    char* wsb = (char*)d_ws;
    const size_t MB = 1024 * 1024;
    u16*   wqkvT = (u16*)(wsb + 0);
    u16*   woT   = (u16*)(wsb + 6 * MB);
    u16*   w1T   = (u16*)(wsb + 8 * MB);
    u16*   w2T   = (u16*)(wsb + 16 * MB);
    u16*   xn    = (u16*)(wsb + 24 * MB);
    float* x2    = (float*)(wsb + 32 * MB);
    u16*   vtp   = (u16*)(wsb + 32 * MB);   // bf16 [2][16][64][2048] perm, 8 MB
    u16*   ctx   = (u16*)(wsb + 48 * MB);
    u16*   qkv   = (u16*)(wsb + 56 * MB);
    u16*   ff1   = (u16*)(wsb + 56 * MB);

    // merged weight transposes: one launch for wq/wk/wv/wo/w1/w2
    transpose_all<<<12288, dim3(32, 8), 0, stream>>>(
        wq, wk, wv, wo, w1, w2,
        wqkvT, woT, w1T, w2T);

    // LN1: xn = LN(x)
    ln_kernel<<<MROWS, 256, 0, stream>>>(x, ln1a, ln1b, xn);
    // QKV GEMM: [4096,1024]@[1024,3072], 128x64 tiles (1536 blocks, 6/CU)
    gemm_bt<4,2,false><<<dim3(3072/64, MROWS/128), 256, 0, stream>>>(xn, wqkvT, qkv,
                                                                     nullptr, nullptr,
                                                                     MROWS, 3072, DMODEL, 0);
    // V transpose (key-permuted) for DMA + b64-P staging
    transpose_v_perm<<<dim3(SEQ/64, BATCH*NHEAD), 256, 0, stream>>>(qkv, vtp);
    // flash attention -> ctx bf16
    flash_attn<<<dim3(SEQ/64, NHEAD, BATCH), 256, 0, stream>>>(qkv, vtp, mask, ctx);
    // O-projection + residual: x2 = x + ctx @ wo, 64x64 tiles, ROW-banded
    // grid (M-tiles=64, N-tiles=16): per-XCD {ctx-slice 1MB + woT 2MB} fits L2
    gemm_bt<2,2,true,true><<<dim3(MROWS/64, DMODEL/64), 256, 0, stream>>>(
        ctx, woT, x2, nullptr, x, MROWS, DMODEL, DMODEL, 0);
    // LN2
    ln_kernel<<<MROWS, 256, 0, stream>>>(x2, ln2a, ln2b, xn);
    // FFN1: ff1 = relu(xn @ w1 + b1), 128x64 tiles (2048 blocks, 6/CU by LDS)
    gemm_bt<4,2,false><<<dim3(DFF_/64, MROWS/128), 256, 0, stream>>>(xn, w1T, ff1,
                                                                    b1, nullptr,
                                                                    MROWS, DFF_, DMODEL, 1);
    // FFN2: out = x2 + ff1 @ w2 + b2, 64x64 tiles, ROW-banded grid (64,16):
    // XCD k owns row-tiles [8k,8k+8) -> ff1 A-slice 4MB L2-resident
    gemm_bt<2,2,true,true><<<dim3(MROWS/64, DMODEL/64), 256, 0, stream>>>(
        ff1, w2T, out, b2, x2, MROWS, DMODEL, DFF_, 0);
}